// Round 3
// baseline (262.133 us; speedup 1.0000x reference)
//
#include <hip/hip_runtime.h>
#include <hip/hip_bf16.h>

typedef __bf16 bf16x8 __attribute__((ext_vector_type(8)));
typedef __bf16 bf16x4 __attribute__((ext_vector_type(4)));
typedef float  f32x4  __attribute__((ext_vector_type(4)));

#define B_  8
#define T_  2048
#define D_  1024
#define HS_ 64

// ---------------------------------------------------------------------------
// Inputs are FP32 (per the reference). Internally we run bf16 MFMA:
//   fp32 x  --(fused cvt in qkv_proj)-->  bf16 A-fragments
//   fp32 W  --(transpose_w)-->            bf16 Wt[3][HS][D]
//   Q,K bf16 [b*T+t][h];  V bf16 transposed Vt[b][h][t];  output fp32.
// ---------------------------------------------------------------------------

// Kernel 0: transpose + downconvert the three [D,HS] fp32 weights to
// bf16 Wt[3][HS][D] so the projection B-fragment is a 16B contiguous load.
__global__ __launch_bounds__(256) void transpose_w(
    const float* __restrict__ Wq, const float* __restrict__ Wk,
    const float* __restrict__ Wv, __bf16* __restrict__ Wt)
{
    int idx = blockIdx.x * 256 + threadIdx.x;     // 0 .. 3*65536-1
    int p   = idx >> 16;
    int rem = idx & 65535;
    int d   = rem >> 6;
    int h   = rem & 63;
    const float* W = (p == 0) ? Wq : (p == 1) ? Wk : Wv;
    Wt[p * 65536 + h * 1024 + d] = (__bf16)W[d * 64 + h];
}

// Kernel 1: QKV projection. x[16384,1024](fp32) @ W[1024,64] + b.
// grid = (256 row-tiles of 64, 3 projections), block = 256 (4 waves).
__global__ __launch_bounds__(256) void qkv_proj(
    const float* __restrict__ x,     // [16384][1024] fp32
    const __bf16* __restrict__ Wt,   // [3][64][1024] bf16
    const float* __restrict__ bq, const float* __restrict__ bk,
    const float* __restrict__ bv,
    __bf16* __restrict__ Q, __bf16* __restrict__ K, __bf16* __restrict__ Vt)
{
    const int p    = blockIdx.y;
    const int rt   = blockIdx.x;
    const int wave = threadIdx.x >> 6;
    const int lane = threadIdx.x & 63;
    const int m16  = lane & 15;
    const int quad = lane >> 4;

    const int row0 = rt * 64 + wave * 16;
    const __bf16* Wtp = Wt + p * 65536;

    f32x4 acc[4];
    #pragma unroll
    for (int s = 0; s < 4; ++s) acc[s] = {0.f, 0.f, 0.f, 0.f};

    const float* xrow = x + (size_t)(row0 + m16) * 1024;
    for (int k0 = 0; k0 < 1024; k0 += 32) {
        // fused fp32 -> bf16 conversion of the A fragment (8 elems/lane)
        f32x4 x0 = *(const f32x4*)(xrow + k0 + quad * 8);
        f32x4 x1 = *(const f32x4*)(xrow + k0 + quad * 8 + 4);
        bf16x8 a;
        #pragma unroll
        for (int j = 0; j < 4; ++j) { a[j] = (__bf16)x0[j]; a[4 + j] = (__bf16)x1[j]; }
        #pragma unroll
        for (int s = 0; s < 4; ++s) {
            bf16x8 bfrag = *(const bf16x8*)(Wtp + (size_t)(s * 16 + m16) * 1024 + k0 + quad * 8);
            acc[s] = __builtin_amdgcn_mfma_f32_16x16x32_bf16(a, bfrag, acc[s], 0, 0, 0);
        }
    }

    const float* bias = (p == 0) ? bq : (p == 1) ? bk : bv;

    if (p == 2) {
        // V transposed: Vt[b][h][t]; C-layout t's are consecutive per reg.
        const int bidx = row0 >> 11;
        const int t0   = (row0 & 2047) + quad * 4;
        #pragma unroll
        for (int s = 0; s < 4; ++s) {
            const int h = s * 16 + m16;
            const float bia = bias[h];
            bf16x4 pack;
            #pragma unroll
            for (int r = 0; r < 4; ++r) pack[r] = (__bf16)(acc[s][r] + bia);
            *(bf16x4*)(Vt + (size_t)bidx * (HS_ * T_) + (size_t)h * T_ + t0) = pack;
        }
    } else {
        __bf16* dst = (p == 0) ? Q : K;
        #pragma unroll
        for (int s = 0; s < 4; ++s) {
            const int h = s * 16 + m16;
            const float bia = bias[h];
            #pragma unroll
            for (int r = 0; r < 4; ++r)
                dst[(size_t)(row0 + quad * 4 + r) * 64 + h] = (__bf16)(acc[s][r] + bia);
        }
    }
}

// Kernel 2: causal flash attention (bf16 MFMA, fp32 output).
// grid = (32 q-tiles, 8 batches), block = 256 (4 waves), wave = 16 q-rows.
__global__ __launch_bounds__(256) void attn(
    const __bf16* __restrict__ Q,   // [8][2048][64]
    const __bf16* __restrict__ K,   // [8][2048][64]
    const __bf16* __restrict__ Vt,  // [8][64][2048]
    float* __restrict__ O)          // [8][2048][64] fp32
{
    __shared__ alignas(16) __bf16 Plds[4][16][64];

    const int b    = blockIdx.y;
    const int qt   = blockIdx.x;
    const int wave = threadIdx.x >> 6;
    const int lane = threadIdx.x & 63;
    const int m16  = lane & 15;
    const int quad = lane >> 4;

    const __bf16* Qb = Q  + (size_t)b * T_ * HS_;
    const __bf16* Kb = K  + (size_t)b * T_ * HS_;
    const __bf16* Vb = Vt + (size_t)b * HS_ * T_;

    const int q0 = qt * 64 + wave * 16;

    bf16x8 qa0 = *(const bf16x8*)(Qb + (size_t)(q0 + m16) * 64 + quad * 8);
    bf16x8 qa1 = *(const bf16x8*)(Qb + (size_t)(q0 + m16) * 64 + 32 + quad * 8);

    f32x4 o_acc[4];
    #pragma unroll
    for (int s = 0; s < 4; ++s) o_acc[s] = {0.f, 0.f, 0.f, 0.f};
    float m_run[4], l_run[4];
    #pragma unroll
    for (int r = 0; r < 4; ++r) { m_run[r] = -1e30f; l_run[r] = 0.f; }

    const int ntiles = qt + 1;      // causal; same for all waves -> uniform barriers
    for (int jt = 0; jt < ntiles; ++jt) {
        const int j0 = jt * 64;

        // S = Q K^T
        f32x4 s[4];
        #pragma unroll
        for (int snb = 0; snb < 4; ++snb) s[snb] = {0.f, 0.f, 0.f, 0.f};
        #pragma unroll
        for (int snb = 0; snb < 4; ++snb) {
            const __bf16* krow = Kb + (size_t)(j0 + snb * 16 + m16) * 64;
            bf16x8 kb0 = *(const bf16x8*)(krow + quad * 8);
            bf16x8 kb1 = *(const bf16x8*)(krow + 32 + quad * 8);
            s[snb] = __builtin_amdgcn_mfma_f32_16x16x32_bf16(qa0, kb0, s[snb], 0, 0, 0);
            s[snb] = __builtin_amdgcn_mfma_f32_16x16x32_bf16(qa1, kb1, s[snb], 0, 0, 0);
        }

        // scale + causal mask + online softmax (C-layout row = quad*4+r)
        #pragma unroll
        for (int r = 0; r < 4; ++r) {
            const int qrow = q0 + quad * 4 + r;
            float mx = -1e30f;
            #pragma unroll
            for (int snb = 0; snb < 4; ++snb) {
                const int key = j0 + snb * 16 + m16;
                float v = s[snb][r] * 0.125f;       // 1/sqrt(64)
                v = (key <= qrow) ? v : -1e30f;
                s[snb][r] = v;
                mx = fmaxf(mx, v);
            }
            mx = fmaxf(mx, __shfl_xor(mx, 1));
            mx = fmaxf(mx, __shfl_xor(mx, 2));
            mx = fmaxf(mx, __shfl_xor(mx, 4));
            mx = fmaxf(mx, __shfl_xor(mx, 8));

            const float newm  = fmaxf(m_run[r], mx);
            const float alpha = __expf(m_run[r] - newm);
            m_run[r] = newm;

            float rs = 0.f;
            #pragma unroll
            for (int snb = 0; snb < 4; ++snb) {
                float pv = __expf(s[snb][r] - newm);
                s[snb][r] = pv;
                rs += pv;
            }
            rs += __shfl_xor(rs, 1);
            rs += __shfl_xor(rs, 2);
            rs += __shfl_xor(rs, 4);
            rs += __shfl_xor(rs, 8);
            l_run[r] = l_run[r] * alpha + rs;

            #pragma unroll
            for (int hs = 0; hs < 4; ++hs) o_acc[hs][r] *= alpha;

            #pragma unroll
            for (int snb = 0; snb < 4; ++snb)
                Plds[wave][quad * 4 + r][snb * 16 + m16] = (__bf16)s[snb][r];
        }

        __syncthreads();   // P-writes visible before vector read
        bf16x8 pa0 = *(const bf16x8*)&Plds[wave][m16][quad * 8];
        bf16x8 pa1 = *(const bf16x8*)&Plds[wave][m16][32 + quad * 8];
        __syncthreads();   // reads done before next tile's writes

        // O += P V
        #pragma unroll
        for (int hs = 0; hs < 4; ++hs) {
            const __bf16* vcol = Vb + (size_t)(hs * 16 + m16) * T_ + j0;
            bf16x8 vb0 = *(const bf16x8*)(vcol + quad * 8);
            bf16x8 vb1 = *(const bf16x8*)(vcol + 32 + quad * 8);
            o_acc[hs] = __builtin_amdgcn_mfma_f32_16x16x32_bf16(pa0, vb0, o_acc[hs], 0, 0, 0);
            o_acc[hs] = __builtin_amdgcn_mfma_f32_16x16x32_bf16(pa1, vb1, o_acc[hs], 0, 0, 0);
        }
    }

    // epilogue: O / l, fp32 store
    float* Ob = O + ((size_t)b * T_ + q0) * 64;
    #pragma unroll
    for (int r = 0; r < 4; ++r) {
        const float inv = 1.f / l_run[r];
        #pragma unroll
        for (int hs = 0; hs < 4; ++hs)
            Ob[(size_t)(quad * 4 + r) * 64 + hs * 16 + m16] = o_acc[hs][r] * inv;
    }
}

// ---------------------------------------------------------------------------
extern "C" void kernel_launch(void* const* d_in, const int* in_sizes, int n_in,
                              void* d_out, int out_size, void* d_ws, size_t ws_size,
                              hipStream_t stream)
{
    const float* x  = (const float*)d_in[0];
    const float* Wq = (const float*)d_in[1];
    const float* bq = (const float*)d_in[2];
    const float* Wk = (const float*)d_in[3];
    const float* bk = (const float*)d_in[4];
    const float* Wv = (const float*)d_in[5];
    const float* bv = (const float*)d_in[6];
    float* out = (float*)d_out;

    __bf16* ws = (__bf16*)d_ws;
    __bf16* Wt = ws;                         // 3*64*1024 = 196608 bf16
    __bf16* Q  = Wt + 3 * 64 * 1024;         // 8*2048*64 = 1048576
    __bf16* K  = Q  + (size_t)B_ * T_ * HS_;
    __bf16* Vt = K  + (size_t)B_ * T_ * HS_; // transposed [b][h][t]

    transpose_w<<<768, 256, 0, stream>>>(Wq, Wk, Wv, Wt);
    qkv_proj<<<dim3(256, 3), 256, 0, stream>>>(x, Wt, bq, bk, bv, Q, K, Vt);
    attn<<<dim3(32, 8), 256, 0, stream>>>(Q, K, Vt, out);
}

// Round 4
// 213.828 us; speedup vs baseline: 1.2259x; 1.2259x over previous
//
#include <hip/hip_runtime.h>
#include <hip/hip_bf16.h>

typedef __bf16 bf16x8 __attribute__((ext_vector_type(8)));
typedef __bf16 bf16x4 __attribute__((ext_vector_type(4)));
typedef float  f32x4  __attribute__((ext_vector_type(4)));

#define B_  8
#define T_  2048
#define D_  1024
#define HS_ 64

// ---------------------------------------------------------------------------
// fp32 inputs/outputs; bf16 MFMA internally.
// Pipeline: transpose_w -> qkv_fused (x read ONCE) -> attn_partial (split-K,
// 8 key-slots per q-tile, online softmax per slot) -> attn_merge (LSE-combine).
// ---------------------------------------------------------------------------

// Kernel 0: transpose + downconvert [D,HS] fp32 weights to bf16 Wt[3][HS][D].
__global__ __launch_bounds__(256) void transpose_w(
    const float* __restrict__ Wq, const float* __restrict__ Wk,
    const float* __restrict__ Wv, __bf16* __restrict__ Wt)
{
    int idx = blockIdx.x * 256 + threadIdx.x;     // 0 .. 3*65536-1
    int p   = idx >> 16;
    int rem = idx & 65535;
    int d   = rem >> 6;
    int h   = rem & 63;
    const float* W = (p == 0) ? Wq : (p == 1) ? Wk : Wv;
    Wt[p * 65536 + h * 1024 + d] = (__bf16)W[d * 64 + h];
}

// Kernel 1: fused QKV projection — single pass over x.
// grid = 256 row-tiles of 64, block = 256 (4 waves, wave = 16 rows).
// Per k-step: 1 A-frag (fp32->bf16 fused) + 12 B-frags + 12 MFMAs.
__global__ __launch_bounds__(256) void qkv_fused(
    const float* __restrict__ x,     // [16384][1024] fp32
    const __bf16* __restrict__ Wt,   // [3][64][1024] bf16
    const float* __restrict__ bq, const float* __restrict__ bk,
    const float* __restrict__ bv,
    __bf16* __restrict__ Q, __bf16* __restrict__ K, __bf16* __restrict__ Vt)
{
    const int rt   = blockIdx.x;
    const int wave = threadIdx.x >> 6;
    const int lane = threadIdx.x & 63;
    const int m16  = lane & 15;
    const int quad = lane >> 4;
    const int row0 = rt * 64 + wave * 16;

    f32x4 acc[3][4];
    #pragma unroll
    for (int p = 0; p < 3; ++p)
        #pragma unroll
        for (int s = 0; s < 4; ++s) acc[p][s] = {0.f, 0.f, 0.f, 0.f};

    const float* xrow = x + (size_t)(row0 + m16) * 1024;
    for (int k0 = 0; k0 < 1024; k0 += 32) {
        f32x4 x0 = *(const f32x4*)(xrow + k0 + quad * 8);
        f32x4 x1 = *(const f32x4*)(xrow + k0 + quad * 8 + 4);
        bf16x8 a;
        #pragma unroll
        for (int j = 0; j < 4; ++j) { a[j] = (__bf16)x0[j]; a[4 + j] = (__bf16)x1[j]; }
        #pragma unroll
        for (int p = 0; p < 3; ++p)
            #pragma unroll
            for (int s = 0; s < 4; ++s) {
                bf16x8 bfrag = *(const bf16x8*)(Wt + p * 65536 +
                                   (size_t)(s * 16 + m16) * 1024 + k0 + quad * 8);
                acc[p][s] = __builtin_amdgcn_mfma_f32_16x16x32_bf16(a, bfrag, acc[p][s], 0, 0, 0);
            }
    }

    // Q epilogue (p=0)
    #pragma unroll
    for (int s = 0; s < 4; ++s) {
        const int h = s * 16 + m16;
        const float bia = bq[h];
        #pragma unroll
        for (int r = 0; r < 4; ++r)
            Q[(size_t)(row0 + quad * 4 + r) * 64 + h] = (__bf16)(acc[0][s][r] + bia);
    }
    // K epilogue (p=1)
    #pragma unroll
    for (int s = 0; s < 4; ++s) {
        const int h = s * 16 + m16;
        const float bia = bk[h];
        #pragma unroll
        for (int r = 0; r < 4; ++r)
            K[(size_t)(row0 + quad * 4 + r) * 64 + h] = (__bf16)(acc[1][s][r] + bia);
    }
    // V epilogue (p=2), transposed Vt[b][h][t]
    {
        const int bidx = row0 >> 11;
        const int t0   = (row0 & 2047) + quad * 4;
        #pragma unroll
        for (int s = 0; s < 4; ++s) {
            const int h = s * 16 + m16;
            const float bia = bv[h];
            bf16x4 pack;
            #pragma unroll
            for (int r = 0; r < 4; ++r) pack[r] = (__bf16)(acc[2][s][r] + bia);
            *(bf16x4*)(Vt + (size_t)bidx * (HS_ * T_) + (size_t)h * T_ + t0) = pack;
        }
    }
}

// Kernel 2: split-K causal attention partials.
// grid = (8 key-slots, 32 q-tiles, 8 batches), block = 256 (4 waves x 16 rows).
// Slot z handles key tiles jt = z, z+8, ... <= qt  (max 4 tiles, balanced).
// Every processed tile has >=1 unmasked key per row (qrow >= qt*64 >= jt*64),
// so m stays finite and l >= 1. Writes unnormalized O_part fp32 + (m,l).
__global__ __launch_bounds__(256) void attn_partial(
    const __bf16* __restrict__ Q,   // [8][2048][64]
    const __bf16* __restrict__ K,   // [8][2048][64]
    const __bf16* __restrict__ Vt,  // [8][64][2048]
    float* __restrict__ Opart,      // [8*32*8][64][64]
    float* __restrict__ Ml)         // [8*32*8][64][2]
{
    __shared__ alignas(16) __bf16 Plds[4][16][64];

    const int z  = blockIdx.x;      // key slot 0..7
    const int qt = blockIdx.y;      // q tile 0..31
    const int b  = blockIdx.z;      // batch
    if (z > qt) return;             // uniform exit, before any barrier

    const int wave = threadIdx.x >> 6;
    const int lane = threadIdx.x & 63;
    const int m16  = lane & 15;
    const int quad = lane >> 4;

    const __bf16* Qb = Q  + (size_t)b * T_ * HS_;
    const __bf16* Kb = K  + (size_t)b * T_ * HS_;
    const __bf16* Vb = Vt + (size_t)b * HS_ * T_;

    const int q0 = qt * 64 + wave * 16;

    bf16x8 qa0 = *(const bf16x8*)(Qb + (size_t)(q0 + m16) * 64 + quad * 8);
    bf16x8 qa1 = *(const bf16x8*)(Qb + (size_t)(q0 + m16) * 64 + 32 + quad * 8);

    f32x4 o_acc[4];
    #pragma unroll
    for (int s = 0; s < 4; ++s) o_acc[s] = {0.f, 0.f, 0.f, 0.f};
    float m_run[4], l_run[4];
    #pragma unroll
    for (int r = 0; r < 4; ++r) { m_run[r] = -1e30f; l_run[r] = 0.f; }

    for (int jt = z; jt <= qt; jt += 8) {       // same count for all 4 waves
        const int j0 = jt * 64;

        // S = Q K^T
        f32x4 s[4];
        #pragma unroll
        for (int snb = 0; snb < 4; ++snb) s[snb] = {0.f, 0.f, 0.f, 0.f};
        #pragma unroll
        for (int snb = 0; snb < 4; ++snb) {
            const __bf16* krow = Kb + (size_t)(j0 + snb * 16 + m16) * 64;
            bf16x8 kb0 = *(const bf16x8*)(krow + quad * 8);
            bf16x8 kb1 = *(const bf16x8*)(krow + 32 + quad * 8);
            s[snb] = __builtin_amdgcn_mfma_f32_16x16x32_bf16(qa0, kb0, s[snb], 0, 0, 0);
            s[snb] = __builtin_amdgcn_mfma_f32_16x16x32_bf16(qa1, kb1, s[snb], 0, 0, 0);
        }

        // scale + causal mask + online softmax (C-layout row = quad*4+r)
        #pragma unroll
        for (int r = 0; r < 4; ++r) {
            const int qrow = q0 + quad * 4 + r;
            float mx = -1e30f;
            #pragma unroll
            for (int snb = 0; snb < 4; ++snb) {
                const int key = j0 + snb * 16 + m16;
                float v = s[snb][r] * 0.125f;       // 1/sqrt(64)
                v = (key <= qrow) ? v : -1e30f;
                s[snb][r] = v;
                mx = fmaxf(mx, v);
            }
            mx = fmaxf(mx, __shfl_xor(mx, 1));
            mx = fmaxf(mx, __shfl_xor(mx, 2));
            mx = fmaxf(mx, __shfl_xor(mx, 4));
            mx = fmaxf(mx, __shfl_xor(mx, 8));

            const float newm  = fmaxf(m_run[r], mx);
            const float alpha = __expf(m_run[r] - newm);
            m_run[r] = newm;

            float rs = 0.f;
            #pragma unroll
            for (int snb = 0; snb < 4; ++snb) {
                float pv = __expf(s[snb][r] - newm);
                s[snb][r] = pv;
                rs += pv;
            }
            rs += __shfl_xor(rs, 1);
            rs += __shfl_xor(rs, 2);
            rs += __shfl_xor(rs, 4);
            rs += __shfl_xor(rs, 8);
            l_run[r] = l_run[r] * alpha + rs;

            #pragma unroll
            for (int hs = 0; hs < 4; ++hs) o_acc[hs][r] *= alpha;

            #pragma unroll
            for (int snb = 0; snb < 4; ++snb)
                Plds[wave][quad * 4 + r][snb * 16 + m16] = (__bf16)s[snb][r];
        }

        __syncthreads();
        bf16x8 pa0 = *(const bf16x8*)&Plds[wave][m16][quad * 8];
        bf16x8 pa1 = *(const bf16x8*)&Plds[wave][m16][32 + quad * 8];
        __syncthreads();

        // O += P V
        #pragma unroll
        for (int hs = 0; hs < 4; ++hs) {
            const __bf16* vcol = Vb + (size_t)(hs * 16 + m16) * T_ + j0;
            bf16x8 vb0 = *(const bf16x8*)(vcol + quad * 8);
            bf16x8 vb1 = *(const bf16x8*)(vcol + 32 + quad * 8);
            o_acc[hs] = __builtin_amdgcn_mfma_f32_16x16x32_bf16(pa0, vb0, o_acc[hs], 0, 0, 0);
            o_acc[hs] = __builtin_amdgcn_mfma_f32_16x16x32_bf16(pa1, vb1, o_acc[hs], 0, 0, 0);
        }
    }

    // epilogue: unnormalized partial O (fp32) + per-row (m, l)
    const int slot = (b * 32 + qt) * 8 + z;
    float* Op = Opart + (size_t)slot * 4096;
    #pragma unroll
    for (int r = 0; r < 4; ++r) {
        const int row = wave * 16 + quad * 4 + r;
        #pragma unroll
        for (int hs = 0; hs < 4; ++hs)
            Op[(size_t)row * 64 + hs * 16 + m16] = o_acc[hs][r];
    }
    if (m16 == 0) {
        #pragma unroll
        for (int r = 0; r < 4; ++r) {
            const int row = wave * 16 + quad * 4 + r;
            Ml[(size_t)slot * 128 + row * 2 + 0] = m_run[r];
            Ml[(size_t)slot * 128 + row * 2 + 1] = l_run[r];
        }
    }
}

// Kernel 3: merge the <=8 slot-partials per q-tile (log-sum-exp weighting).
// grid = (32 q-tiles, 8 batches), block = 256: thread = (row = tid>>2,
// colblk = tid&3) -> 16 contiguous floats; wave reads 4KB contiguous.
__global__ __launch_bounds__(256) void attn_merge(
    const float* __restrict__ Opart, const float* __restrict__ Ml,
    float* __restrict__ O)
{
    const int qt = blockIdx.x;
    const int b  = blockIdx.y;
    const int tid = threadIdx.x;
    const int row = tid >> 2;
    const int colblk = tid & 3;
    const int nc = (qt + 1 < 8) ? qt + 1 : 8;
    const int slotBase = (b * 32 + qt) * 8;

    f32x4 acc[4];
    #pragma unroll
    for (int j = 0; j < 4; ++j) acc[j] = {0.f, 0.f, 0.f, 0.f};
    float M = -1e30f, den = 0.f;

    for (int c = 0; c < nc; ++c) {
        const float* mlp = Ml + (size_t)(slotBase + c) * 128 + row * 2;
        const float mc = mlp[0];
        const float lc = mlp[1];
        const float newM  = fmaxf(M, mc);
        const float alpha = __expf(M - newM);
        const float w     = __expf(mc - newM);
        M = newM;

        const float* op = Opart + (size_t)(slotBase + c) * 4096 + row * 64 + colblk * 16;
        #pragma unroll
        for (int j = 0; j < 4; ++j) {
            f32x4 v = *(const f32x4*)(op + j * 4);
            #pragma unroll
            for (int e = 0; e < 4; ++e) acc[j][e] = acc[j][e] * alpha + w * v[e];
        }
        den = den * alpha + w * lc;
    }

    const float inv = 1.f / den;
    float* out = O + ((size_t)b * T_ + qt * 64 + row) * 64 + colblk * 16;
    #pragma unroll
    for (int j = 0; j < 4; ++j) {
        f32x4 v;
        #pragma unroll
        for (int e = 0; e < 4; ++e) v[e] = acc[j][e] * inv;
        *(f32x4*)(out + j * 4) = v;
    }
}

// ---------------------------------------------------------------------------
extern "C" void kernel_launch(void* const* d_in, const int* in_sizes, int n_in,
                              void* d_out, int out_size, void* d_ws, size_t ws_size,
                              hipStream_t stream)
{
    const float* x  = (const float*)d_in[0];
    const float* Wq = (const float*)d_in[1];
    const float* bq = (const float*)d_in[2];
    const float* Wk = (const float*)d_in[3];
    const float* bk = (const float*)d_in[4];
    const float* Wv = (const float*)d_in[5];
    const float* bv = (const float*)d_in[6];
    float* out = (float*)d_out;

    __bf16* Wt = (__bf16*)d_ws;              // 3*64*1024 bf16       = 0.4 MB
    __bf16* Q  = Wt + 3 * 64 * 1024;         // 8*2048*64 bf16       = 2 MB
    __bf16* K  = Q  + (size_t)B_ * T_ * HS_;
    __bf16* Vt = K  + (size_t)B_ * T_ * HS_; // transposed [b][h][t]
    float* Opart = (float*)(Vt + (size_t)B_ * T_ * HS_);  // 2048*4096 f32 = 33.6 MB
    float* Ml    = Opart + (size_t)2048 * 4096;           // 2048*128  f32 =  1 MB

    transpose_w<<<768, 256, 0, stream>>>(Wq, Wk, Wv, Wt);
    qkv_fused<<<256, 256, 0, stream>>>(x, Wt, bq, bk, bv, Q, K, Vt);
    attn_partial<<<dim3(8, 32, 8), 256, 0, stream>>>(Q, K, Vt, Opart, Ml);
    attn_merge<<<dim3(32, 8), 256, 0, stream>>>(Opart, Ml, out);
}

// Round 5
// 211.282 us; speedup vs baseline: 1.2407x; 1.0121x over previous
//
#include <hip/hip_runtime.h>
#include <hip/hip_bf16.h>

typedef __bf16 bf16x8 __attribute__((ext_vector_type(8)));
typedef __bf16 bf16x4 __attribute__((ext_vector_type(4)));
typedef float  f32x4  __attribute__((ext_vector_type(4)));

#define B_  8
#define T_  2048
#define D_  1024
#define HS_ 64

// ---------------------------------------------------------------------------
// fp32 inputs/outputs; bf16 MFMA internally.
// transpose_w -> qkv_fused (split-K across 4 waves, LDS reduce)
//             -> attn_partial (split-K flash, 8 slots) -> attn_merge (LSE).
// ---------------------------------------------------------------------------

// Kernel 0: transpose + downconvert [D,HS] fp32 weights to bf16 Wt[3][HS][D].
__global__ __launch_bounds__(256) void transpose_w(
    const float* __restrict__ Wq, const float* __restrict__ Wk,
    const float* __restrict__ Wv, __bf16* __restrict__ Wt)
{
    int idx = blockIdx.x * 256 + threadIdx.x;     // 0 .. 3*65536-1
    int p   = idx >> 16;
    int rem = idx & 65535;
    int d   = rem >> 6;
    int h   = rem & 63;
    const float* W = (p == 0) ? Wq : (p == 1) ? Wk : Wv;
    Wt[p * 65536 + h * 1024 + d] = (__bf16)W[d * 64 + h];
}

// Kernel 1: fused QKV projection, K-split across waves.
// grid = 1024 blocks (16 rows each), block = 256 = 4 waves.
// Wave w accumulates x[rows, w*256:(w+1)*256] @ W[w*256:(w+1)*256, :] for all
// 3 projections (12 MFMA accs). Waves 1-3 dump accs to LDS (36 KB); wave 0
// adds and runs the epilogue. 4 blocks/CU -> 16 waves/CU (vs 4 before):
// the round-4 66us was pure latency at 1 wave/SIMD.
__global__ __launch_bounds__(256) void qkv_fused(
    const float* __restrict__ x,     // [16384][1024] fp32
    const __bf16* __restrict__ Wt,   // [3][64][1024] bf16
    const float* __restrict__ bq, const float* __restrict__ bk,
    const float* __restrict__ bv,
    __bf16* __restrict__ Q, __bf16* __restrict__ K, __bf16* __restrict__ Vt)
{
    __shared__ f32x4 Red[3][12][64];              // 36864 B

    const int rt   = blockIdx.x;                  // 0..1023
    const int wave = threadIdx.x >> 6;            // K-slice owner
    const int lane = threadIdx.x & 63;
    const int m16  = lane & 15;
    const int quad = lane >> 4;
    const int row0 = rt * 16;

    f32x4 acc[3][4];
    #pragma unroll
    for (int p = 0; p < 3; ++p)
        #pragma unroll
        for (int s = 0; s < 4; ++s) acc[p][s] = {0.f, 0.f, 0.f, 0.f};

    const float* xrow = x + (size_t)(row0 + m16) * 1024 + wave * 256;
    const __bf16* wbase = Wt + wave * 256;
    for (int k0 = 0; k0 < 256; k0 += 32) {
        f32x4 x0 = *(const f32x4*)(xrow + k0 + quad * 8);
        f32x4 x1 = *(const f32x4*)(xrow + k0 + quad * 8 + 4);
        bf16x8 a;
        #pragma unroll
        for (int j = 0; j < 4; ++j) { a[j] = (__bf16)x0[j]; a[4 + j] = (__bf16)x1[j]; }
        #pragma unroll
        for (int p = 0; p < 3; ++p)
            #pragma unroll
            for (int s = 0; s < 4; ++s) {
                bf16x8 bfrag = *(const bf16x8*)(wbase + p * 65536 +
                                   (size_t)(s * 16 + m16) * 1024 + k0 + quad * 8);
                acc[p][s] = __builtin_amdgcn_mfma_f32_16x16x32_bf16(a, bfrag, acc[p][s], 0, 0, 0);
            }
    }

    if (wave != 0) {
        #pragma unroll
        for (int p = 0; p < 3; ++p)
            #pragma unroll
            for (int s = 0; s < 4; ++s)
                Red[wave - 1][p * 4 + s][lane] = acc[p][s];
    }
    __syncthreads();
    if (wave != 0) return;

    // wave 0: reduce + epilogue
    #pragma unroll
    for (int p = 0; p < 3; ++p)
        #pragma unroll
        for (int s = 0; s < 4; ++s) {
            f32x4 sum = acc[p][s];
            #pragma unroll
            for (int w = 0; w < 3; ++w) {
                f32x4 v = Red[w][p * 4 + s][lane];
                #pragma unroll
                for (int e = 0; e < 4; ++e) sum[e] += v[e];
            }
            acc[p][s] = sum;
        }

    // Q epilogue (p=0)
    #pragma unroll
    for (int s = 0; s < 4; ++s) {
        const int h = s * 16 + m16;
        const float bia = bq[h];
        #pragma unroll
        for (int r = 0; r < 4; ++r)
            Q[(size_t)(row0 + quad * 4 + r) * 64 + h] = (__bf16)(acc[0][s][r] + bia);
    }
    // K epilogue (p=1)
    #pragma unroll
    for (int s = 0; s < 4; ++s) {
        const int h = s * 16 + m16;
        const float bia = bk[h];
        #pragma unroll
        for (int r = 0; r < 4; ++r)
            K[(size_t)(row0 + quad * 4 + r) * 64 + h] = (__bf16)(acc[1][s][r] + bia);
    }
    // V epilogue (p=2), transposed Vt[b][h][t]; 16-row tiles never cross batch
    {
        const int bidx = row0 >> 11;
        const int t0   = (row0 & 2047) + quad * 4;
        #pragma unroll
        for (int s = 0; s < 4; ++s) {
            const int h = s * 16 + m16;
            const float bia = bv[h];
            bf16x4 pack;
            #pragma unroll
            for (int r = 0; r < 4; ++r) pack[r] = (__bf16)(acc[2][s][r] + bia);
            *(bf16x4*)(Vt + (size_t)bidx * (HS_ * T_) + (size_t)h * T_ + t0) = pack;
        }
    }
}

// Kernel 2: split-K causal attention partials.
// grid = (8 key-slots, 32 q-tiles, 8 batches), block = 256 (4 waves x 16 rows).
__global__ __launch_bounds__(256) void attn_partial(
    const __bf16* __restrict__ Q,   // [8][2048][64]
    const __bf16* __restrict__ K,   // [8][2048][64]
    const __bf16* __restrict__ Vt,  // [8][64][2048]
    float* __restrict__ Opart,      // [8*32*8][64][64]
    float* __restrict__ Ml)         // [8*32*8][64][2]
{
    __shared__ alignas(16) __bf16 Plds[4][16][64];

    const int z  = blockIdx.x;      // key slot 0..7
    const int qt = blockIdx.y;      // q tile 0..31
    const int b  = blockIdx.z;      // batch
    if (z > qt) return;             // uniform exit, before any barrier

    const int wave = threadIdx.x >> 6;
    const int lane = threadIdx.x & 63;
    const int m16  = lane & 15;
    const int quad = lane >> 4;

    const __bf16* Qb = Q  + (size_t)b * T_ * HS_;
    const __bf16* Kb = K  + (size_t)b * T_ * HS_;
    const __bf16* Vb = Vt + (size_t)b * HS_ * T_;

    const int q0 = qt * 64 + wave * 16;

    bf16x8 qa0 = *(const bf16x8*)(Qb + (size_t)(q0 + m16) * 64 + quad * 8);
    bf16x8 qa1 = *(const bf16x8*)(Qb + (size_t)(q0 + m16) * 64 + 32 + quad * 8);

    f32x4 o_acc[4];
    #pragma unroll
    for (int s = 0; s < 4; ++s) o_acc[s] = {0.f, 0.f, 0.f, 0.f};
    float m_run[4], l_run[4];
    #pragma unroll
    for (int r = 0; r < 4; ++r) { m_run[r] = -1e30f; l_run[r] = 0.f; }

    for (int jt = z; jt <= qt; jt += 8) {       // same count for all 4 waves
        const int j0 = jt * 64;

        // S = Q K^T
        f32x4 s[4];
        #pragma unroll
        for (int snb = 0; snb < 4; ++snb) s[snb] = {0.f, 0.f, 0.f, 0.f};
        #pragma unroll
        for (int snb = 0; snb < 4; ++snb) {
            const __bf16* krow = Kb + (size_t)(j0 + snb * 16 + m16) * 64;
            bf16x8 kb0 = *(const bf16x8*)(krow + quad * 8);
            bf16x8 kb1 = *(const bf16x8*)(krow + 32 + quad * 8);
            s[snb] = __builtin_amdgcn_mfma_f32_16x16x32_bf16(qa0, kb0, s[snb], 0, 0, 0);
            s[snb] = __builtin_amdgcn_mfma_f32_16x16x32_bf16(qa1, kb1, s[snb], 0, 0, 0);
        }

        // scale + causal mask + online softmax (C-layout row = quad*4+r)
        #pragma unroll
        for (int r = 0; r < 4; ++r) {
            const int qrow = q0 + quad * 4 + r;
            float mx = -1e30f;
            #pragma unroll
            for (int snb = 0; snb < 4; ++snb) {
                const int key = j0 + snb * 16 + m16;
                float v = s[snb][r] * 0.125f;       // 1/sqrt(64)
                v = (key <= qrow) ? v : -1e30f;
                s[snb][r] = v;
                mx = fmaxf(mx, v);
            }
            mx = fmaxf(mx, __shfl_xor(mx, 1));
            mx = fmaxf(mx, __shfl_xor(mx, 2));
            mx = fmaxf(mx, __shfl_xor(mx, 4));
            mx = fmaxf(mx, __shfl_xor(mx, 8));

            const float newm  = fmaxf(m_run[r], mx);
            const float alpha = __expf(m_run[r] - newm);
            m_run[r] = newm;

            float rs = 0.f;
            #pragma unroll
            for (int snb = 0; snb < 4; ++snb) {
                float pv = __expf(s[snb][r] - newm);
                s[snb][r] = pv;
                rs += pv;
            }
            rs += __shfl_xor(rs, 1);
            rs += __shfl_xor(rs, 2);
            rs += __shfl_xor(rs, 4);
            rs += __shfl_xor(rs, 8);
            l_run[r] = l_run[r] * alpha + rs;

            #pragma unroll
            for (int hs = 0; hs < 4; ++hs) o_acc[hs][r] *= alpha;

            #pragma unroll
            for (int snb = 0; snb < 4; ++snb)
                Plds[wave][quad * 4 + r][snb * 16 + m16] = (__bf16)s[snb][r];
        }

        __syncthreads();
        bf16x8 pa0 = *(const bf16x8*)&Plds[wave][m16][quad * 8];
        bf16x8 pa1 = *(const bf16x8*)&Plds[wave][m16][32 + quad * 8];
        __syncthreads();

        // O += P V
        #pragma unroll
        for (int hs = 0; hs < 4; ++hs) {
            const __bf16* vcol = Vb + (size_t)(hs * 16 + m16) * T_ + j0;
            bf16x8 vb0 = *(const bf16x8*)(vcol + quad * 8);
            bf16x8 vb1 = *(const bf16x8*)(vcol + 32 + quad * 8);
            o_acc[hs] = __builtin_amdgcn_mfma_f32_16x16x32_bf16(pa0, vb0, o_acc[hs], 0, 0, 0);
            o_acc[hs] = __builtin_amdgcn_mfma_f32_16x16x32_bf16(pa1, vb1, o_acc[hs], 0, 0, 0);
        }
    }

    // epilogue: unnormalized partial O (fp32) + per-row (m, l)
    const int slot = (b * 32 + qt) * 8 + z;
    float* Op = Opart + (size_t)slot * 4096;
    #pragma unroll
    for (int r = 0; r < 4; ++r) {
        const int row = wave * 16 + quad * 4 + r;
        #pragma unroll
        for (int hs = 0; hs < 4; ++hs)
            Op[(size_t)row * 64 + hs * 16 + m16] = o_acc[hs][r];
    }
    if (m16 == 0) {
        #pragma unroll
        for (int r = 0; r < 4; ++r) {
            const int row = wave * 16 + quad * 4 + r;
            Ml[(size_t)slot * 128 + row * 2 + 0] = m_run[r];
            Ml[(size_t)slot * 128 + row * 2 + 1] = l_run[r];
        }
    }
}

// Kernel 3: merge the <=8 slot-partials per q-tile (log-sum-exp weighting).
__global__ __launch_bounds__(256) void attn_merge(
    const float* __restrict__ Opart, const float* __restrict__ Ml,
    float* __restrict__ O)
{
    const int qt = blockIdx.x;
    const int b  = blockIdx.y;
    const int tid = threadIdx.x;
    const int row = tid >> 2;
    const int colblk = tid & 3;
    const int nc = (qt + 1 < 8) ? qt + 1 : 8;
    const int slotBase = (b * 32 + qt) * 8;

    f32x4 acc[4];
    #pragma unroll
    for (int j = 0; j < 4; ++j) acc[j] = {0.f, 0.f, 0.f, 0.f};
    float M = -1e30f, den = 0.f;

    for (int c = 0; c < nc; ++c) {
        const float* mlp = Ml + (size_t)(slotBase + c) * 128 + row * 2;
        const float mc = mlp[0];
        const float lc = mlp[1];
        const float newM  = fmaxf(M, mc);
        const float alpha = __expf(M - newM);
        const float w     = __expf(mc - newM);
        M = newM;

        const float* op = Opart + (size_t)(slotBase + c) * 4096 + row * 64 + colblk * 16;
        #pragma unroll
        for (int j = 0; j < 4; ++j) {
            f32x4 v = *(const f32x4*)(op + j * 4);
            #pragma unroll
            for (int e = 0; e < 4; ++e) acc[j][e] = acc[j][e] * alpha + w * v[e];
        }
        den = den * alpha + w * lc;
    }

    const float inv = 1.f / den;
    float* out = O + ((size_t)b * T_ + qt * 64 + row) * 64 + colblk * 16;
    #pragma unroll
    for (int j = 0; j < 4; ++j) {
        f32x4 v;
        #pragma unroll
        for (int e = 0; e < 4; ++e) v[e] = acc[j][e] * inv;
        *(f32x4*)(out + j * 4) = v;
    }
}

// ---------------------------------------------------------------------------
extern "C" void kernel_launch(void* const* d_in, const int* in_sizes, int n_in,
                              void* d_out, int out_size, void* d_ws, size_t ws_size,
                              hipStream_t stream)
{
    const float* x  = (const float*)d_in[0];
    const float* Wq = (const float*)d_in[1];
    const float* bq = (const float*)d_in[2];
    const float* Wk = (const float*)d_in[3];
    const float* bk = (const float*)d_in[4];
    const float* Wv = (const float*)d_in[5];
    const float* bv = (const float*)d_in[6];
    float* out = (float*)d_out;

    __bf16* Wt = (__bf16*)d_ws;              // 3*64*1024 bf16       = 0.4 MB
    __bf16* Q  = Wt + 3 * 64 * 1024;         // 8*2048*64 bf16       = 2 MB
    __bf16* K  = Q  + (size_t)B_ * T_ * HS_;
    __bf16* Vt = K  + (size_t)B_ * T_ * HS_; // transposed [b][h][t]
    float* Opart = (float*)(Vt + (size_t)B_ * T_ * HS_);  // 2048*4096 f32 = 33.6 MB
    float* Ml    = Opart + (size_t)2048 * 4096;           // 2048*128  f32 =  1 MB

    transpose_w<<<768, 256, 0, stream>>>(Wq, Wk, Wv, Wt);
    qkv_fused<<<1024, 256, 0, stream>>>(x, Wt, bq, bk, bv, Q, K, Vt);
    attn_partial<<<dim3(8, 32, 8), 256, 0, stream>>>(Q, K, Vt, Opart, Ml);
    attn_merge<<<dim3(32, 8), 256, 0, stream>>>(Opart, Ml, out);
}

// Round 6
// 183.839 us; speedup vs baseline: 1.4259x; 1.1493x over previous
//
#include <hip/hip_runtime.h>
#include <hip/hip_bf16.h>

typedef __bf16 bf16x8 __attribute__((ext_vector_type(8)));
typedef __bf16 bf16x4 __attribute__((ext_vector_type(4)));
typedef float  f32x4  __attribute__((ext_vector_type(4)));

#define B_  8
#define T_  2048
#define D_  1024
#define HS_ 64

// ---------------------------------------------------------------------------
// fp32 inputs/outputs; bf16 MFMA internally.
// pack_w (W -> MFMA-fragment-ordered Wp) -> qkv_fused (LDS-staged x, split-K
// across 4 waves, LDS reduce) -> attn_partial (split-K flash) -> attn_merge.
//
// Round-5 lesson: 12 B-frag gathers (16 scattered lines each) + 2 x gathers
// (32 lines) per k-step saturated the vector-memory front end (~256 lines/
// k-step ~ 4.5 cyc/line == the invariant 65us). Fix: fragment-packed W
// (contiguous 1KB/wave loads) + coalesced x staging through LDS.
// ---------------------------------------------------------------------------

// Kernel 0: pack the three [D,HS] fp32 weights into bf16 MFMA-fragment order:
// Wp[pg][lane*8+j] with pg = ((p*32 + c)*4 + s), holding
// W_p[c*32 + (lane>>4)*8 + j][s*16 + (lane&15)].  One-time 0.4 MB.
__global__ __launch_bounds__(256) void pack_w(
    const float* __restrict__ Wq, const float* __restrict__ Wk,
    const float* __restrict__ Wv, __bf16* __restrict__ Wp)
{
    const int t    = blockIdx.x * 256 + threadIdx.x;   // 0..24575
    const int lane = t & 63;
    const int pg   = t >> 6;                           // 0..383
    const int s    = pg & 3;
    const int c    = (pg >> 2) & 31;
    const int p    = pg >> 7;
    const int m16  = lane & 15;
    const int quad = lane >> 4;

    const float* W = (p == 0) ? Wq : (p == 1) ? Wk : Wv;
    const float* src = W + (size_t)(c * 32 + quad * 8) * 64 + s * 16 + m16;
    bf16x8 frag;
    #pragma unroll
    for (int j = 0; j < 8; ++j) frag[j] = (__bf16)src[(size_t)j * 64];
    *(bf16x8*)(Wp + (size_t)pg * 512 + lane * 8) = frag;
}

// Kernel 1: fused QKV projection, K-split across waves, LDS-staged x.
// grid = 1024 blocks (16 rows each), block = 256 = 4 waves.
// Wave w owns K-slice [w*256,(w+1)*256). Per k-step (32 cols):
//   - stage 16x32 fp32 coalesced (8 lanes/row, 128B runs) -> bf16 LDS
//     (row stride 40 elems = 80B: 16B-aligned, frag reads 2-way = free)
//   - 1 ds_read_b128 A-frag + 12 contiguous 1KB Wp loads + 12 MFMAs.
// Waves 1-3 dump accs to LDS; wave 0 reduces + epilogue.
__global__ __launch_bounds__(256) void qkv_fused(
    const float* __restrict__ x,     // [16384][1024] fp32
    const __bf16* __restrict__ Wp,   // [384][512] fragment-packed bf16
    const float* __restrict__ bq, const float* __restrict__ bk,
    const float* __restrict__ bv,
    __bf16* __restrict__ Q, __bf16* __restrict__ K, __bf16* __restrict__ Vt)
{
    __shared__ f32x4 Red[3][12][64];                  // 36864 B
    __shared__ alignas(16) __bf16 Xs[4][16][40];      //  5120 B (padded)

    const int rt   = blockIdx.x;                  // 0..1023
    const int wave = threadIdx.x >> 6;            // K-slice owner
    const int lane = threadIdx.x & 63;
    const int m16  = lane & 15;
    const int quad = lane >> 4;
    const int row0 = rt * 16;

    f32x4 acc[3][4];
    #pragma unroll
    for (int p = 0; p < 3; ++p)
        #pragma unroll
        for (int s = 0; s < 4; ++s) acc[p][s] = {0.f, 0.f, 0.f, 0.f};

    const int ld_c4 = (lane & 7) * 4;             // float4 col within 32
    const int ld_r  = lane >> 3;                  // row 0..7 (+8 on 2nd load)

    for (int k0 = 0; k0 < 256; k0 += 32) {
        // ---- stage 16 rows x 32 cols, coalesced, fp32 -> bf16 ----
        #pragma unroll
        for (int ld = 0; ld < 2; ++ld) {
            const int r = ld * 8 + ld_r;
            f32x4 v = *(const f32x4*)(x + (size_t)(row0 + r) * 1024 +
                                      wave * 256 + k0 + ld_c4);
            bf16x4 w;
            #pragma unroll
            for (int e = 0; e < 4; ++e) w[e] = (__bf16)v[e];
            *(bf16x4*)&Xs[wave][r][ld_c4] = w;
        }
        __syncthreads();   // writes visible before cross-lane frag read

        bf16x8 a = *(const bf16x8*)&Xs[wave][m16][quad * 8];

        const int cbase = wave * 8 + (k0 >> 5);
        #pragma unroll
        for (int p = 0; p < 3; ++p)
            #pragma unroll
            for (int s = 0; s < 4; ++s) {
                bf16x8 bfrag = *(const bf16x8*)(Wp +
                    ((size_t)((p * 32 + cbase) * 4 + s) << 9) + lane * 8);
                acc[p][s] = __builtin_amdgcn_mfma_f32_16x16x32_bf16(a, bfrag, acc[p][s], 0, 0, 0);
            }
    }

    if (wave != 0) {
        #pragma unroll
        for (int p = 0; p < 3; ++p)
            #pragma unroll
            for (int s = 0; s < 4; ++s)
                Red[wave - 1][p * 4 + s][lane] = acc[p][s];
    }
    __syncthreads();
    if (wave != 0) return;

    // wave 0: reduce + epilogue
    #pragma unroll
    for (int p = 0; p < 3; ++p)
        #pragma unroll
        for (int s = 0; s < 4; ++s) {
            f32x4 sum = acc[p][s];
            #pragma unroll
            for (int w = 0; w < 3; ++w) {
                f32x4 v = Red[w][p * 4 + s][lane];
                #pragma unroll
                for (int e = 0; e < 4; ++e) sum[e] += v[e];
            }
            acc[p][s] = sum;
        }

    // Q epilogue (p=0)
    #pragma unroll
    for (int s = 0; s < 4; ++s) {
        const int h = s * 16 + m16;
        const float bia = bq[h];
        #pragma unroll
        for (int r = 0; r < 4; ++r)
            Q[(size_t)(row0 + quad * 4 + r) * 64 + h] = (__bf16)(acc[0][s][r] + bia);
    }
    // K epilogue (p=1)
    #pragma unroll
    for (int s = 0; s < 4; ++s) {
        const int h = s * 16 + m16;
        const float bia = bk[h];
        #pragma unroll
        for (int r = 0; r < 4; ++r)
            K[(size_t)(row0 + quad * 4 + r) * 64 + h] = (__bf16)(acc[1][s][r] + bia);
    }
    // V epilogue (p=2), transposed Vt[b][h][t]; 16-row tiles never cross batch
    {
        const int bidx = row0 >> 11;
        const int t0   = (row0 & 2047) + quad * 4;
        #pragma unroll
        for (int s = 0; s < 4; ++s) {
            const int h = s * 16 + m16;
            const float bia = bv[h];
            bf16x4 pack;
            #pragma unroll
            for (int r = 0; r < 4; ++r) pack[r] = (__bf16)(acc[2][s][r] + bia);
            *(bf16x4*)(Vt + (size_t)bidx * (HS_ * T_) + (size_t)h * T_ + t0) = pack;
        }
    }
}

// Kernel 2: split-K causal attention partials.
// grid = (8 key-slots, 32 q-tiles, 8 batches), block = 256 (4 waves x 16 rows).
__global__ __launch_bounds__(256) void attn_partial(
    const __bf16* __restrict__ Q,   // [8][2048][64]
    const __bf16* __restrict__ K,   // [8][2048][64]
    const __bf16* __restrict__ Vt,  // [8][64][2048]
    float* __restrict__ Opart,      // [8*32*8][64][64]
    float* __restrict__ Ml)         // [8*32*8][64][2]
{
    __shared__ alignas(16) __bf16 Plds[4][16][64];

    const int z  = blockIdx.x;      // key slot 0..7
    const int qt = blockIdx.y;      // q tile 0..31
    const int b  = blockIdx.z;      // batch
    if (z > qt) return;             // uniform exit, before any barrier

    const int wave = threadIdx.x >> 6;
    const int lane = threadIdx.x & 63;
    const int m16  = lane & 15;
    const int quad = lane >> 4;

    const __bf16* Qb = Q  + (size_t)b * T_ * HS_;
    const __bf16* Kb = K  + (size_t)b * T_ * HS_;
    const __bf16* Vb = Vt + (size_t)b * HS_ * T_;

    const int q0 = qt * 64 + wave * 16;

    bf16x8 qa0 = *(const bf16x8*)(Qb + (size_t)(q0 + m16) * 64 + quad * 8);
    bf16x8 qa1 = *(const bf16x8*)(Qb + (size_t)(q0 + m16) * 64 + 32 + quad * 8);

    f32x4 o_acc[4];
    #pragma unroll
    for (int s = 0; s < 4; ++s) o_acc[s] = {0.f, 0.f, 0.f, 0.f};
    float m_run[4], l_run[4];
    #pragma unroll
    for (int r = 0; r < 4; ++r) { m_run[r] = -1e30f; l_run[r] = 0.f; }

    for (int jt = z; jt <= qt; jt += 8) {       // same count for all 4 waves
        const int j0 = jt * 64;

        // S = Q K^T
        f32x4 s[4];
        #pragma unroll
        for (int snb = 0; snb < 4; ++snb) s[snb] = {0.f, 0.f, 0.f, 0.f};
        #pragma unroll
        for (int snb = 0; snb < 4; ++snb) {
            const __bf16* krow = Kb + (size_t)(j0 + snb * 16 + m16) * 64;
            bf16x8 kb0 = *(const bf16x8*)(krow + quad * 8);
            bf16x8 kb1 = *(const bf16x8*)(krow + 32 + quad * 8);
            s[snb] = __builtin_amdgcn_mfma_f32_16x16x32_bf16(qa0, kb0, s[snb], 0, 0, 0);
            s[snb] = __builtin_amdgcn_mfma_f32_16x16x32_bf16(qa1, kb1, s[snb], 0, 0, 0);
        }

        // scale + causal mask + online softmax (C-layout row = quad*4+r)
        #pragma unroll
        for (int r = 0; r < 4; ++r) {
            const int qrow = q0 + quad * 4 + r;
            float mx = -1e30f;
            #pragma unroll
            for (int snb = 0; snb < 4; ++snb) {
                const int key = j0 + snb * 16 + m16;
                float v = s[snb][r] * 0.125f;       // 1/sqrt(64)
                v = (key <= qrow) ? v : -1e30f;
                s[snb][r] = v;
                mx = fmaxf(mx, v);
            }
            mx = fmaxf(mx, __shfl_xor(mx, 1));
            mx = fmaxf(mx, __shfl_xor(mx, 2));
            mx = fmaxf(mx, __shfl_xor(mx, 4));
            mx = fmaxf(mx, __shfl_xor(mx, 8));

            const float newm  = fmaxf(m_run[r], mx);
            const float alpha = __expf(m_run[r] - newm);
            m_run[r] = newm;

            float rs = 0.f;
            #pragma unroll
            for (int snb = 0; snb < 4; ++snb) {
                float pv = __expf(s[snb][r] - newm);
                s[snb][r] = pv;
                rs += pv;
            }
            rs += __shfl_xor(rs, 1);
            rs += __shfl_xor(rs, 2);
            rs += __shfl_xor(rs, 4);
            rs += __shfl_xor(rs, 8);
            l_run[r] = l_run[r] * alpha + rs;

            #pragma unroll
            for (int hs = 0; hs < 4; ++hs) o_acc[hs][r] *= alpha;

            #pragma unroll
            for (int snb = 0; snb < 4; ++snb)
                Plds[wave][quad * 4 + r][snb * 16 + m16] = (__bf16)s[snb][r];
        }

        __syncthreads();
        bf16x8 pa0 = *(const bf16x8*)&Plds[wave][m16][quad * 8];
        bf16x8 pa1 = *(const bf16x8*)&Plds[wave][m16][32 + quad * 8];
        __syncthreads();

        // O += P V
        #pragma unroll
        for (int hs = 0; hs < 4; ++hs) {
            const __bf16* vcol = Vb + (size_t)(hs * 16 + m16) * T_ + j0;
            bf16x8 vb0 = *(const bf16x8*)(vcol + quad * 8);
            bf16x8 vb1 = *(const bf16x8*)(vcol + 32 + quad * 8);
            o_acc[hs] = __builtin_amdgcn_mfma_f32_16x16x32_bf16(pa0, vb0, o_acc[hs], 0, 0, 0);
            o_acc[hs] = __builtin_amdgcn_mfma_f32_16x16x32_bf16(pa1, vb1, o_acc[hs], 0, 0, 0);
        }
    }

    // epilogue: unnormalized partial O (fp32) + per-row (m, l)
    const int slot = (b * 32 + qt) * 8 + z;
    float* Op = Opart + (size_t)slot * 4096;
    #pragma unroll
    for (int r = 0; r < 4; ++r) {
        const int row = wave * 16 + quad * 4 + r;
        #pragma unroll
        for (int hs = 0; hs < 4; ++hs)
            Op[(size_t)row * 64 + hs * 16 + m16] = o_acc[hs][r];
    }
    if (m16 == 0) {
        #pragma unroll
        for (int r = 0; r < 4; ++r) {
            const int row = wave * 16 + quad * 4 + r;
            Ml[(size_t)slot * 128 + row * 2 + 0] = m_run[r];
            Ml[(size_t)slot * 128 + row * 2 + 1] = l_run[r];
        }
    }
}

// Kernel 3: merge the <=8 slot-partials per q-tile (log-sum-exp weighting).
__global__ __launch_bounds__(256) void attn_merge(
    const float* __restrict__ Opart, const float* __restrict__ Ml,
    float* __restrict__ O)
{
    const int qt = blockIdx.x;
    const int b  = blockIdx.y;
    const int tid = threadIdx.x;
    const int row = tid >> 2;
    const int colblk = tid & 3;
    const int nc = (qt + 1 < 8) ? qt + 1 : 8;
    const int slotBase = (b * 32 + qt) * 8;

    f32x4 acc[4];
    #pragma unroll
    for (int j = 0; j < 4; ++j) acc[j] = {0.f, 0.f, 0.f, 0.f};
    float M = -1e30f, den = 0.f;

    for (int c = 0; c < nc; ++c) {
        const float* mlp = Ml + (size_t)(slotBase + c) * 128 + row * 2;
        const float mc = mlp[0];
        const float lc = mlp[1];
        const float newM  = fmaxf(M, mc);
        const float alpha = __expf(M - newM);
        const float w     = __expf(mc - newM);
        M = newM;

        const float* op = Opart + (size_t)(slotBase + c) * 4096 + row * 64 + colblk * 16;
        #pragma unroll
        for (int j = 0; j < 4; ++j) {
            f32x4 v = *(const f32x4*)(op + j * 4);
            #pragma unroll
            for (int e = 0; e < 4; ++e) acc[j][e] = acc[j][e] * alpha + w * v[e];
        }
        den = den * alpha + w * lc;
    }

    const float inv = 1.f / den;
    float* out = O + ((size_t)b * T_ + qt * 64 + row) * 64 + colblk * 16;
    #pragma unroll
    for (int j = 0; j < 4; ++j) {
        f32x4 v;
        #pragma unroll
        for (int e = 0; e < 4; ++e) v[e] = acc[j][e] * inv;
        *(f32x4*)(out + j * 4) = v;
    }
}

// ---------------------------------------------------------------------------
extern "C" void kernel_launch(void* const* d_in, const int* in_sizes, int n_in,
                              void* d_out, int out_size, void* d_ws, size_t ws_size,
                              hipStream_t stream)
{
    const float* x  = (const float*)d_in[0];
    const float* Wq = (const float*)d_in[1];
    const float* bq = (const float*)d_in[2];
    const float* Wk = (const float*)d_in[3];
    const float* bk = (const float*)d_in[4];
    const float* Wv = (const float*)d_in[5];
    const float* bv = (const float*)d_in[6];
    float* out = (float*)d_out;

    __bf16* Wp = (__bf16*)d_ws;              // 384*512 bf16         = 0.4 MB
    __bf16* Q  = Wp + 384 * 512;             // 8*2048*64 bf16       = 2 MB
    __bf16* K  = Q  + (size_t)B_ * T_ * HS_;
    __bf16* Vt = K  + (size_t)B_ * T_ * HS_; // transposed [b][h][t]
    float* Opart = (float*)(Vt + (size_t)B_ * T_ * HS_);  // 2048*4096 f32 = 33.6 MB
    float* Ml    = Opart + (size_t)2048 * 4096;           // 2048*128  f32 =  1 MB

    pack_w<<<96, 256, 0, stream>>>(Wq, Wk, Wv, Wp);
    qkv_fused<<<1024, 256, 0, stream>>>(x, Wp, bq, bk, bv, Q, K, Vt);
    attn_partial<<<dim3(8, 32, 8), 256, 0, stream>>>(Q, K, Vt, Opart, Ml);
    attn_merge<<<dim3(32, 8), 256, 0, stream>>>(Opart, Ml, out);
}

// Round 7
// 158.639 us; speedup vs baseline: 1.6524x; 1.1589x over previous
//
#include <hip/hip_runtime.h>
#include <hip/hip_bf16.h>

typedef __bf16 bf16x8 __attribute__((ext_vector_type(8)));
typedef __bf16 bf16x4 __attribute__((ext_vector_type(4)));
typedef float  f32x4  __attribute__((ext_vector_type(4)));

#define B_  8
#define T_  2048
#define D_  1024
#define HS_ 64

// ---------------------------------------------------------------------------
// fp32 inputs/outputs; bf16 MFMA internally.
// pack_w -> qkv_fused -> attn_partial (S^T scheme: P stays in registers;
// K/V staged once per block into fragment-packed LDS) -> attn_merge.
//
// Round-6 lesson: attn_partial was DS-pipe-bound (50 DS ops/tile/wave: 32
// shuffles + P LDS round-trip; 946k bank conflicts) with 4x-redundant K/V
// reads. S^T + key-permutation makes the softmaxed C-layout registers a
// valid PV B-operand directly (4 shuffles, zero P movement), and block-level
// staging cuts vmem lines 4x.
// ---------------------------------------------------------------------------

// Kernel 0: pack the three [D,HS] fp32 weights into bf16 MFMA-fragment order.
__global__ __launch_bounds__(256) void pack_w(
    const float* __restrict__ Wq, const float* __restrict__ Wk,
    const float* __restrict__ Wv, __bf16* __restrict__ Wp)
{
    const int t    = blockIdx.x * 256 + threadIdx.x;   // 0..24575
    const int lane = t & 63;
    const int pg   = t >> 6;                           // 0..383
    const int s    = pg & 3;
    const int c    = (pg >> 2) & 31;
    const int p    = pg >> 7;
    const int m16  = lane & 15;
    const int quad = lane >> 4;

    const float* W = (p == 0) ? Wq : (p == 1) ? Wk : Wv;
    const float* src = W + (size_t)(c * 32 + quad * 8) * 64 + s * 16 + m16;
    bf16x8 frag;
    #pragma unroll
    for (int j = 0; j < 8; ++j) frag[j] = (__bf16)src[(size_t)j * 64];
    *(bf16x8*)(Wp + (size_t)pg * 512 + lane * 8) = frag;
}

// Kernel 1: fused QKV projection, K-split across waves, LDS-staged x.
// grid = 1024 blocks (16 rows each), block = 256 = 4 waves.
// Xs round-trip is intra-wave -> __threadfence_block (no barrier rendezvous).
__global__ __launch_bounds__(256) void qkv_fused(
    const float* __restrict__ x,     // [16384][1024] fp32
    const __bf16* __restrict__ Wp,   // [384][512] fragment-packed bf16
    const float* __restrict__ bq, const float* __restrict__ bk,
    const float* __restrict__ bv,
    __bf16* __restrict__ Q, __bf16* __restrict__ K, __bf16* __restrict__ Vt)
{
    __shared__ f32x4 Red[3][12][64];                  // 36864 B
    __shared__ alignas(16) __bf16 Xs[4][16][40];      //  5120 B (padded)

    const int rt   = blockIdx.x;                  // 0..1023
    const int wave = threadIdx.x >> 6;            // K-slice owner
    const int lane = threadIdx.x & 63;
    const int m16  = lane & 15;
    const int quad = lane >> 4;
    const int row0 = rt * 16;

    f32x4 acc[3][4];
    #pragma unroll
    for (int p = 0; p < 3; ++p)
        #pragma unroll
        for (int s = 0; s < 4; ++s) acc[p][s] = {0.f, 0.f, 0.f, 0.f};

    const int ld_c4 = (lane & 7) * 4;             // float4 col within 32
    const int ld_r  = lane >> 3;                  // row 0..7 (+8 on 2nd load)

    for (int k0 = 0; k0 < 256; k0 += 32) {
        // stage 16 rows x 32 cols, coalesced, fp32 -> bf16 (intra-wave only)
        #pragma unroll
        for (int ld = 0; ld < 2; ++ld) {
            const int r = ld * 8 + ld_r;
            f32x4 v = *(const f32x4*)(x + (size_t)(row0 + r) * 1024 +
                                      wave * 256 + k0 + ld_c4);
            bf16x4 w;
            #pragma unroll
            for (int e = 0; e < 4; ++e) w[e] = (__bf16)v[e];
            *(bf16x4*)&Xs[wave][r][ld_c4] = w;
        }
        __threadfence_block();   // order writes before cross-lane frag read

        bf16x8 a = *(const bf16x8*)&Xs[wave][m16][quad * 8];

        const int cbase = wave * 8 + (k0 >> 5);
        #pragma unroll
        for (int p = 0; p < 3; ++p)
            #pragma unroll
            for (int s = 0; s < 4; ++s) {
                bf16x8 bfrag = *(const bf16x8*)(Wp +
                    ((size_t)((p * 32 + cbase) * 4 + s) << 9) + lane * 8);
                acc[p][s] = __builtin_amdgcn_mfma_f32_16x16x32_bf16(a, bfrag, acc[p][s], 0, 0, 0);
            }
    }

    if (wave != 0) {
        #pragma unroll
        for (int p = 0; p < 3; ++p)
            #pragma unroll
            for (int s = 0; s < 4; ++s)
                Red[wave - 1][p * 4 + s][lane] = acc[p][s];
    }
    __syncthreads();
    if (wave != 0) return;

    // wave 0: reduce + epilogue
    #pragma unroll
    for (int p = 0; p < 3; ++p)
        #pragma unroll
        for (int s = 0; s < 4; ++s) {
            f32x4 sum = acc[p][s];
            #pragma unroll
            for (int w = 0; w < 3; ++w) {
                f32x4 v = Red[w][p * 4 + s][lane];
                #pragma unroll
                for (int e = 0; e < 4; ++e) sum[e] += v[e];
            }
            acc[p][s] = sum;
        }

    // Q epilogue (p=0)
    #pragma unroll
    for (int s = 0; s < 4; ++s) {
        const int h = s * 16 + m16;
        const float bia = bq[h];
        #pragma unroll
        for (int r = 0; r < 4; ++r)
            Q[(size_t)(row0 + quad * 4 + r) * 64 + h] = (__bf16)(acc[0][s][r] + bia);
    }
    // K epilogue (p=1)
    #pragma unroll
    for (int s = 0; s < 4; ++s) {
        const int h = s * 16 + m16;
        const float bia = bk[h];
        #pragma unroll
        for (int r = 0; r < 4; ++r)
            K[(size_t)(row0 + quad * 4 + r) * 64 + h] = (__bf16)(acc[1][s][r] + bia);
    }
    // V epilogue (p=2), transposed Vt[b][h][t]
    {
        const int bidx = row0 >> 11;
        const int t0   = (row0 & 2047) + quad * 4;
        #pragma unroll
        for (int s = 0; s < 4; ++s) {
            const int h = s * 16 + m16;
            const float bia = bv[h];
            bf16x4 pack;
            #pragma unroll
            for (int r = 0; r < 4; ++r) pack[r] = (__bf16)(acc[2][s][r] + bia);
            *(bf16x4*)(Vt + (size_t)bidx * (HS_ * T_) + (size_t)h * T_ + t0) = pack;
        }
    }
}

// Kernel 2: split-K causal attention partials, S^T scheme.
// grid = (8 key-slots, 32 q-tiles, 8 batches), block = 256 (4 waves x 16 q).
// Per tile: stage K,V (16KB) frag-packed into LDS once per block; S^T =
// K.Q^T with permuted K rows (phys = (snb>>1)*32 + quad*8 + (snb&1)*4 + r)
// so post-softmax C-layout registers ARE the PV B-operand; O^T = Vt.P^T.
__global__ __launch_bounds__(256) void attn_partial(
    const __bf16* __restrict__ Q,   // [8][2048][64]
    const __bf16* __restrict__ K,   // [8][2048][64]
    const __bf16* __restrict__ Vt,  // [8][64][2048]
    float* __restrict__ Opart,      // [8*32*8][64][64]
    float* __restrict__ Ml)         // [8*32*8][64][2]
{
    __shared__ alignas(16) __bf16 Klds[8 * 512];   // 8 frag-groups x 1KB
    __shared__ alignas(16) __bf16 Vlds[8 * 512];

    const int z  = blockIdx.x;      // key slot 0..7
    const int qt = blockIdx.y;      // q tile 0..31
    const int b  = blockIdx.z;      // batch
    if (z > qt) return;             // uniform exit, before any barrier

    const int tid  = threadIdx.x;
    const int wave = tid >> 6;
    const int lane = tid & 63;
    const int m16  = lane & 15;
    const int quad = lane >> 4;

    const __bf16* Qb = Q  + (size_t)b * T_ * HS_;
    const __bf16* Kb = K  + (size_t)b * T_ * HS_;
    const __bf16* Vb = Vt + (size_t)b * HS_ * T_;

    const int q0   = qt * 64 + wave * 16;
    const int qrow = q0 + m16;                    // this lane's q row

    // Q as B-operand (n=q, k=d): same per-lane data as an A-frag row load
    bf16x8 qb0 = *(const bf16x8*)(Qb + (size_t)qrow * 64 + quad * 8);
    bf16x8 qb1 = *(const bf16x8*)(Qb + (size_t)qrow * 64 + 32 + quad * 8);

    f32x4 o[4];                                   // O^T: h=hs*16+quad*4+r, q=m16
    #pragma unroll
    for (int hs = 0; hs < 4; ++hs) o[hs] = {0.f, 0.f, 0.f, 0.f};
    float m_run = -1e30f, l_run = 0.f;

    for (int jt = z; jt <= qt; jt += 8) {         // uniform trip count in block
        const int j0 = jt * 64;

        // ---- stage K,V tile (8KB each) frag-packed; coalesced 16B/thread x2
        #pragma unroll
        for (int i = 0; i < 2; ++i) {
            const int p    = i * 256 + tid;       // piece 0..511
            const int trow = p >> 3;              // 0..63
            const int tcol = p & 7;               // 8-elem chunk
            // K: permuted row -> (snb, m) per phys = (snb>>1)*32+(m>>2)*8+(snb&1)*4+(m&3)
            bf16x8 kv = *(const bf16x8*)(Kb + (size_t)(j0 + trow) * 64 + tcol * 8);
            const int snb = ((trow >> 5) << 1) | ((trow >> 2) & 1);
            const int mk  = (((trow >> 3) & 3) << 2) | (trow & 3);
            *(bf16x8*)&Klds[((((snb << 1) | (tcol >> 2)) << 6) + (tcol & 3) * 16 + mk) * 8] = kv;
            // V: natural rows (h), key-chunks
            bf16x8 vv = *(const bf16x8*)(Vb + (size_t)trow * T_ + j0 + tcol * 8);
            *(bf16x8*)&Vlds[(((((trow >> 4) << 1) | (tcol >> 2)) << 6) + (tcol & 3) * 16 + (trow & 15)) * 8] = vv;
        }
        __syncthreads();

        // ---- S^T = K.Q^T : A = permuted K rows, B = Q rows ----
        f32x4 s[4];
        #pragma unroll
        for (int snb = 0; snb < 4; ++snb) s[snb] = {0.f, 0.f, 0.f, 0.f};
        #pragma unroll
        for (int snb = 0; snb < 4; ++snb) {
            bf16x8 ka0 = *(const bf16x8*)&Klds[((snb * 2 + 0) * 64 + lane) * 8];
            bf16x8 ka1 = *(const bf16x8*)&Klds[((snb * 2 + 1) * 64 + lane) * 8];
            s[snb] = __builtin_amdgcn_mfma_f32_16x16x32_bf16(ka0, qb0, s[snb], 0, 0, 0);
            s[snb] = __builtin_amdgcn_mfma_f32_16x16x32_bf16(ka1, qb1, s[snb], 0, 0, 0);
        }

        // ---- softmax: lane holds 16 keys of q=qrow; 2+2 shuffles total ----
        float mx = -1e30f;
        #pragma unroll
        for (int snb = 0; snb < 4; ++snb) {
            const int kbase = j0 + ((snb >> 1) << 5) + (quad << 3) + ((snb & 1) << 2);
            #pragma unroll
            for (int r = 0; r < 4; ++r) {
                float v = s[snb][r] * 0.125f;             // 1/sqrt(64)
                v = (kbase + r <= qrow) ? v : -1e30f;     // causal (phys key)
                s[snb][r] = v;
                mx = fmaxf(mx, v);
            }
        }
        mx = fmaxf(mx, __shfl_xor(mx, 16));
        mx = fmaxf(mx, __shfl_xor(mx, 32));

        const float newm  = fmaxf(m_run, mx);
        const float alpha = __expf(m_run - newm);
        m_run = newm;

        float rs = 0.f;
        #pragma unroll
        for (int snb = 0; snb < 4; ++snb)
            #pragma unroll
            for (int r = 0; r < 4; ++r) {
                float pv = __expf(s[snb][r] - newm);
                s[snb][r] = pv;
                rs += pv;
            }
        rs += __shfl_xor(rs, 16);
        rs += __shfl_xor(rs, 32);
        l_run = l_run * alpha + rs;

        #pragma unroll
        for (int hs = 0; hs < 4; ++hs)
            #pragma unroll
            for (int r = 0; r < 4; ++r) o[hs][r] *= alpha;

        // ---- P^T (registers) -> PV B-operand: key = j0+kc*32+quad*8+j,
        //      j = (snb&1)*4 + r  (the staged K permutation makes this exact)
        bf16x8 pb0, pb1;
        #pragma unroll
        for (int r = 0; r < 4; ++r) {
            pb0[r]     = (__bf16)s[0][r];
            pb0[4 + r] = (__bf16)s[1][r];
            pb1[r]     = (__bf16)s[2][r];
            pb1[4 + r] = (__bf16)s[3][r];
        }

        // ---- O^T += Vt . P^T ----
        #pragma unroll
        for (int hs = 0; hs < 4; ++hs) {
            bf16x8 va0 = *(const bf16x8*)&Vlds[((hs * 2 + 0) * 64 + lane) * 8];
            bf16x8 va1 = *(const bf16x8*)&Vlds[((hs * 2 + 1) * 64 + lane) * 8];
            o[hs] = __builtin_amdgcn_mfma_f32_16x16x32_bf16(va0, pb0, o[hs], 0, 0, 0);
            o[hs] = __builtin_amdgcn_mfma_f32_16x16x32_bf16(va1, pb1, o[hs], 0, 0, 0);
        }
        __syncthreads();   // LDS reads done before next tile's staging
    }

    // epilogue: Opart[q][h] fp32 (16B stores), Ml per q
    const int slot = (b * 32 + qt) * 8 + z;
    float* Op = Opart + (size_t)slot * 4096;
    #pragma unroll
    for (int hs = 0; hs < 4; ++hs)
        *(f32x4*)(Op + (size_t)(wave * 16 + m16) * 64 + hs * 16 + quad * 4) = o[hs];
    if (quad == 0) {
        Ml[(size_t)slot * 128 + (wave * 16 + m16) * 2 + 0] = m_run;
        Ml[(size_t)slot * 128 + (wave * 16 + m16) * 2 + 1] = l_run;
    }
}

// Kernel 3: merge the <=8 slot-partials per q-tile (log-sum-exp weighting).
__global__ __launch_bounds__(256) void attn_merge(
    const float* __restrict__ Opart, const float* __restrict__ Ml,
    float* __restrict__ O)
{
    const int qt = blockIdx.x;
    const int b  = blockIdx.y;
    const int tid = threadIdx.x;
    const int row = tid >> 2;
    const int colblk = tid & 3;
    const int nc = (qt + 1 < 8) ? qt + 1 : 8;
    const int slotBase = (b * 32 + qt) * 8;

    f32x4 acc[4];
    #pragma unroll
    for (int j = 0; j < 4; ++j) acc[j] = {0.f, 0.f, 0.f, 0.f};
    float M = -1e30f, den = 0.f;

    for (int c = 0; c < nc; ++c) {
        const float* mlp = Ml + (size_t)(slotBase + c) * 128 + row * 2;
        const float mc = mlp[0];
        const float lc = mlp[1];
        const float newM  = fmaxf(M, mc);
        const float alpha = __expf(M - newM);
        const float w     = __expf(mc - newM);
        M = newM;

        const float* op = Opart + (size_t)(slotBase + c) * 4096 + row * 64 + colblk * 16;
        #pragma unroll
        for (int j = 0; j < 4; ++j) {
            f32x4 v = *(const f32x4*)(op + j * 4);
            #pragma unroll
            for (int e = 0; e < 4; ++e) acc[j][e] = acc[j][e] * alpha + w * v[e];
        }
        den = den * alpha + w * lc;
    }

    const float inv = 1.f / den;
    float* out = O + ((size_t)b * T_ + qt * 64 + row) * 64 + colblk * 16;
    #pragma unroll
    for (int j = 0; j < 4; ++j) {
        f32x4 v;
        #pragma unroll
        for (int e = 0; e < 4; ++e) v[e] = acc[j][e] * inv;
        *(f32x4*)(out + j * 4) = v;
    }
}

// ---------------------------------------------------------------------------
extern "C" void kernel_launch(void* const* d_in, const int* in_sizes, int n_in,
                              void* d_out, int out_size, void* d_ws, size_t ws_size,
                              hipStream_t stream)
{
    const float* x  = (const float*)d_in[0];
    const float* Wq = (const float*)d_in[1];
    const float* bq = (const float*)d_in[2];
    const float* Wk = (const float*)d_in[3];
    const float* bk = (const float*)d_in[4];
    const float* Wv = (const float*)d_in[5];
    const float* bv = (const float*)d_in[6];
    float* out = (float*)d_out;

    __bf16* Wp = (__bf16*)d_ws;              // 384*512 bf16         = 0.4 MB
    __bf16* Q  = Wp + 384 * 512;             // 8*2048*64 bf16       = 2 MB
    __bf16* K  = Q  + (size_t)B_ * T_ * HS_;
    __bf16* Vt = K  + (size_t)B_ * T_ * HS_; // transposed [b][h][t]
    float* Opart = (float*)(Vt + (size_t)B_ * T_ * HS_);  // 2048*4096 f32 = 33.6 MB
    float* Ml    = Opart + (size_t)2048 * 4096;           // 2048*128  f32 =  1 MB

    pack_w<<<96, 256, 0, stream>>>(Wq, Wk, Wv, Wp);
    qkv_fused<<<1024, 256, 0, stream>>>(x, Wp, bq, bk, bv, Q, K, Vt);
    attn_partial<<<dim3(8, 32, 8), 256, 0, stream>>>(Q, K, Vt, Opart, Ml);
    attn_merge<<<dim3(32, 8), 256, 0, stream>>>(Opart, Ml, out);
}

// Round 8
// 156.580 us; speedup vs baseline: 1.6741x; 1.0131x over previous
//
#include <hip/hip_runtime.h>
#include <hip/hip_bf16.h>

typedef __bf16 bf16x8 __attribute__((ext_vector_type(8)));
typedef __bf16 bf16x4 __attribute__((ext_vector_type(4)));
typedef float  f32x4  __attribute__((ext_vector_type(4)));

#define B_  8
#define T_  2048
#define D_  1024
#define HS_ 64

// ---------------------------------------------------------------------------
// fp32 inputs/outputs; bf16 MFMA internally.
// pack_w -> qkv_fused (up-front LDS staging, fence-free k-loop)
//        -> attn_partial (S^T scheme, register-resident P) -> attn_merge.
//
// Round-7 lesson: per-k-step __threadfence_block() == s_waitcnt vmcnt(0)
// drained all in-flight loads 8x per wave -> the invariant ~41us. Fix:
// stage the whole 16x256 x-slice once, then a pure load+MFMA stream.
// ---------------------------------------------------------------------------

// Kernel 0: pack the three [D,HS] fp32 weights into bf16 MFMA-fragment order.
__global__ __launch_bounds__(256) void pack_w(
    const float* __restrict__ Wq, const float* __restrict__ Wk,
    const float* __restrict__ Wv, __bf16* __restrict__ Wp)
{
    const int t    = blockIdx.x * 256 + threadIdx.x;   // 0..24575
    const int lane = t & 63;
    const int pg   = t >> 6;                           // 0..383
    const int s    = pg & 3;
    const int c    = (pg >> 2) & 31;
    const int p    = pg >> 7;
    const int m16  = lane & 15;
    const int quad = lane >> 4;

    const float* W = (p == 0) ? Wq : (p == 1) ? Wk : Wv;
    const float* src = W + (size_t)(c * 32 + quad * 8) * 64 + s * 16 + m16;
    bf16x8 frag;
    #pragma unroll
    for (int j = 0; j < 8; ++j) frag[j] = (__bf16)src[(size_t)j * 64];
    *(bf16x8*)(Wp + (size_t)pg * 512 + lane * 8) = frag;
}

// Kernel 1: fused QKV projection, K-split across waves.
// grid = 1024 blocks (16 rows each), block = 256 = 4 waves.
// Phase 1: each wave stages its 16x256 x-slice fp32->bf16 into LDS
//   (coalesced 1KB runs, 16 independent loads -> fully pipelined).
// Phase 2: 8 fence-free k-steps: ds_read_b128 A-frag (stride 264 -> 2-way
//   conflict = free) + 12 contiguous 1KB Wp loads + 12 MFMAs.
// Phase 3: cross-wave reduce through Red (unioned with dead Xs) + epilogue.
__global__ __launch_bounds__(256) void qkv_fused(
    const float* __restrict__ x,     // [16384][1024] fp32
    const __bf16* __restrict__ Wp,   // [384][512] fragment-packed bf16
    const float* __restrict__ bq, const float* __restrict__ bk,
    const float* __restrict__ bv,
    __bf16* __restrict__ Q, __bf16* __restrict__ K, __bf16* __restrict__ Vt)
{
    __shared__ alignas(16) unsigned char Smem[36864];  // Xs (33792) ∪ Red (36864)

    const int rt   = blockIdx.x;                  // 0..1023
    const int wave = threadIdx.x >> 6;            // K-slice owner
    const int lane = threadIdx.x & 63;
    const int m16  = lane & 15;
    const int quad = lane >> 4;
    const int row0 = rt * 16;

    __bf16* Xs = (__bf16*)(Smem + wave * 8448);   // 16 rows x 264 (pad 8)

    // ---- Phase 1: stage x-slice (16 rows x 256 cols), fp32 -> bf16 ----
    {
        const float* xsrc = x + (size_t)row0 * 1024 + wave * 256;
        const int sr = lane >> 5;                 // 0..1
        const int sc = (lane & 31) * 8;           // 0..248
        #pragma unroll
        for (int i = 0; i < 8; ++i) {
            const int r = i * 2 + sr;
            f32x4 v0 = *(const f32x4*)(xsrc + (size_t)r * 1024 + sc);
            f32x4 v1 = *(const f32x4*)(xsrc + (size_t)r * 1024 + sc + 4);
            bf16x8 w;
            #pragma unroll
            for (int e = 0; e < 4; ++e) { w[e] = (__bf16)v0[e]; w[4 + e] = (__bf16)v1[e]; }
            *(bf16x8*)&Xs[r * 264 + sc] = w;
        }
    }
    __builtin_amdgcn_wave_barrier();   // free: pins DS write->read order for compiler

    // ---- Phase 2: fence-free K-loop ----
    f32x4 acc[3][4];
    #pragma unroll
    for (int p = 0; p < 3; ++p)
        #pragma unroll
        for (int s = 0; s < 4; ++s) acc[p][s] = {0.f, 0.f, 0.f, 0.f};

    for (int k0 = 0; k0 < 256; k0 += 32) {
        bf16x8 a = *(const bf16x8*)&Xs[m16 * 264 + k0 + quad * 8];
        const int cbase = wave * 8 + (k0 >> 5);
        #pragma unroll
        for (int p = 0; p < 3; ++p)
            #pragma unroll
            for (int s = 0; s < 4; ++s) {
                bf16x8 bfrag = *(const bf16x8*)(Wp +
                    ((size_t)((p * 32 + cbase) * 4 + s) << 9) + lane * 8);
                acc[p][s] = __builtin_amdgcn_mfma_f32_16x16x32_bf16(a, bfrag, acc[p][s], 0, 0, 0);
            }
    }

    // ---- Phase 3: cross-wave reduce (Red overlays dead Xs) + epilogue ----
    f32x4* Red = (f32x4*)Smem;                    // [3][12][64]
    __syncthreads();                              // all Xs reads done
    if (wave != 0) {
        #pragma unroll
        for (int p = 0; p < 3; ++p)
            #pragma unroll
            for (int s = 0; s < 4; ++s)
                Red[((wave - 1) * 12 + p * 4 + s) * 64 + lane] = acc[p][s];
    }
    __syncthreads();
    if (wave != 0) return;

    #pragma unroll
    for (int p = 0; p < 3; ++p)
        #pragma unroll
        for (int s = 0; s < 4; ++s) {
            f32x4 sum = acc[p][s];
            #pragma unroll
            for (int w = 0; w < 3; ++w) {
                f32x4 v = Red[(w * 12 + p * 4 + s) * 64 + lane];
                #pragma unroll
                for (int e = 0; e < 4; ++e) sum[e] += v[e];
            }
            acc[p][s] = sum;
        }

    // Q epilogue (p=0)
    #pragma unroll
    for (int s = 0; s < 4; ++s) {
        const int h = s * 16 + m16;
        const float bia = bq[h];
        #pragma unroll
        for (int r = 0; r < 4; ++r)
            Q[(size_t)(row0 + quad * 4 + r) * 64 + h] = (__bf16)(acc[0][s][r] + bia);
    }
    // K epilogue (p=1)
    #pragma unroll
    for (int s = 0; s < 4; ++s) {
        const int h = s * 16 + m16;
        const float bia = bk[h];
        #pragma unroll
        for (int r = 0; r < 4; ++r)
            K[(size_t)(row0 + quad * 4 + r) * 64 + h] = (__bf16)(acc[1][s][r] + bia);
    }
    // V epilogue (p=2), transposed Vt[b][h][t]
    {
        const int bidx = row0 >> 11;
        const int t0   = (row0 & 2047) + quad * 4;
        #pragma unroll
        for (int s = 0; s < 4; ++s) {
            const int h = s * 16 + m16;
            const float bia = bv[h];
            bf16x4 pack;
            #pragma unroll
            for (int r = 0; r < 4; ++r) pack[r] = (__bf16)(acc[2][s][r] + bia);
            *(bf16x4*)(Vt + (size_t)bidx * (HS_ * T_) + (size_t)h * T_ + t0) = pack;
        }
    }
}

// Kernel 2: split-K causal attention partials, S^T scheme.
// grid = (8 key-slots, 32 q-tiles, 8 batches), block = 256 (4 waves x 16 q).
__global__ __launch_bounds__(256) void attn_partial(
    const __bf16* __restrict__ Q,   // [8][2048][64]
    const __bf16* __restrict__ K,   // [8][2048][64]
    const __bf16* __restrict__ Vt,  // [8][64][2048]
    float* __restrict__ Opart,      // [8*32*8][64][64]
    float* __restrict__ Ml)         // [8*32*8][64][2]
{
    __shared__ alignas(16) __bf16 Klds[8 * 512];   // 8 frag-groups x 1KB
    __shared__ alignas(16) __bf16 Vlds[8 * 512];

    const int z  = blockIdx.x;      // key slot 0..7
    const int qt = blockIdx.y;      // q tile 0..31
    const int b  = blockIdx.z;      // batch
    if (z > qt) return;             // uniform exit, before any barrier

    const int tid  = threadIdx.x;
    const int wave = tid >> 6;
    const int lane = tid & 63;
    const int m16  = lane & 15;
    const int quad = lane >> 4;

    const __bf16* Qb = Q  + (size_t)b * T_ * HS_;
    const __bf16* Kb = K  + (size_t)b * T_ * HS_;
    const __bf16* Vb = Vt + (size_t)b * HS_ * T_;

    const int q0   = qt * 64 + wave * 16;
    const int qrow = q0 + m16;                    // this lane's q row

    bf16x8 qb0 = *(const bf16x8*)(Qb + (size_t)qrow * 64 + quad * 8);
    bf16x8 qb1 = *(const bf16x8*)(Qb + (size_t)qrow * 64 + 32 + quad * 8);

    f32x4 o[4];                                   // O^T: h=hs*16+quad*4+r, q=m16
    #pragma unroll
    for (int hs = 0; hs < 4; ++hs) o[hs] = {0.f, 0.f, 0.f, 0.f};
    float m_run = -1e30f, l_run = 0.f;

    for (int jt = z; jt <= qt; jt += 8) {         // uniform trip count in block
        const int j0 = jt * 64;

        // stage K,V tile frag-packed; coalesced 16B/thread x2
        #pragma unroll
        for (int i = 0; i < 2; ++i) {
            const int p    = i * 256 + tid;       // piece 0..511
            const int trow = p >> 3;              // 0..63
            const int tcol = p & 7;               // 8-elem chunk
            bf16x8 kv = *(const bf16x8*)(Kb + (size_t)(j0 + trow) * 64 + tcol * 8);
            const int snb = ((trow >> 5) << 1) | ((trow >> 2) & 1);
            const int mk  = (((trow >> 3) & 3) << 2) | (trow & 3);
            *(bf16x8*)&Klds[((((snb << 1) | (tcol >> 2)) << 6) + (tcol & 3) * 16 + mk) * 8] = kv;
            bf16x8 vv = *(const bf16x8*)(Vb + (size_t)trow * T_ + j0 + tcol * 8);
            *(bf16x8*)&Vlds[(((((trow >> 4) << 1) | (tcol >> 2)) << 6) + (tcol & 3) * 16 + (trow & 15)) * 8] = vv;
        }
        __syncthreads();

        // S^T = K.Q^T
        f32x4 s[4];
        #pragma unroll
        for (int snb = 0; snb < 4; ++snb) s[snb] = {0.f, 0.f, 0.f, 0.f};
        #pragma unroll
        for (int snb = 0; snb < 4; ++snb) {
            bf16x8 ka0 = *(const bf16x8*)&Klds[((snb * 2 + 0) * 64 + lane) * 8];
            bf16x8 ka1 = *(const bf16x8*)&Klds[((snb * 2 + 1) * 64 + lane) * 8];
            s[snb] = __builtin_amdgcn_mfma_f32_16x16x32_bf16(ka0, qb0, s[snb], 0, 0, 0);
            s[snb] = __builtin_amdgcn_mfma_f32_16x16x32_bf16(ka1, qb1, s[snb], 0, 0, 0);
        }

        // softmax: lane holds 16 keys of q=qrow; 2+2 shuffles total
        float mx = -1e30f;
        #pragma unroll
        for (int snb = 0; snb < 4; ++snb) {
            const int kbase = j0 + ((snb >> 1) << 5) + (quad << 3) + ((snb & 1) << 2);
            #pragma unroll
            for (int r = 0; r < 4; ++r) {
                float v = s[snb][r] * 0.125f;             // 1/sqrt(64)
                v = (kbase + r <= qrow) ? v : -1e30f;     // causal (phys key)
                s[snb][r] = v;
                mx = fmaxf(mx, v);
            }
        }
        mx = fmaxf(mx, __shfl_xor(mx, 16));
        mx = fmaxf(mx, __shfl_xor(mx, 32));

        const float newm  = fmaxf(m_run, mx);
        const float alpha = __expf(m_run - newm);
        m_run = newm;

        float rs = 0.f;
        #pragma unroll
        for (int snb = 0; snb < 4; ++snb)
            #pragma unroll
            for (int r = 0; r < 4; ++r) {
                float pv = __expf(s[snb][r] - newm);
                s[snb][r] = pv;
                rs += pv;
            }
        rs += __shfl_xor(rs, 16);
        rs += __shfl_xor(rs, 32);
        l_run = l_run * alpha + rs;

        #pragma unroll
        for (int hs = 0; hs < 4; ++hs)
            #pragma unroll
            for (int r = 0; r < 4; ++r) o[hs][r] *= alpha;

        // P^T (registers) -> PV B-operand directly
        bf16x8 pb0, pb1;
        #pragma unroll
        for (int r = 0; r < 4; ++r) {
            pb0[r]     = (__bf16)s[0][r];
            pb0[4 + r] = (__bf16)s[1][r];
            pb1[r]     = (__bf16)s[2][r];
            pb1[4 + r] = (__bf16)s[3][r];
        }

        // O^T += Vt . P^T
        #pragma unroll
        for (int hs = 0; hs < 4; ++hs) {
            bf16x8 va0 = *(const bf16x8*)&Vlds[((hs * 2 + 0) * 64 + lane) * 8];
            bf16x8 va1 = *(const bf16x8*)&Vlds[((hs * 2 + 1) * 64 + lane) * 8];
            o[hs] = __builtin_amdgcn_mfma_f32_16x16x32_bf16(va0, pb0, o[hs], 0, 0, 0);
            o[hs] = __builtin_amdgcn_mfma_f32_16x16x32_bf16(va1, pb1, o[hs], 0, 0, 0);
        }
        __syncthreads();   // LDS reads done before next tile's staging
    }

    // epilogue: Opart[q][h] fp32 (16B stores), Ml per q
    const int slot = (b * 32 + qt) * 8 + z;
    float* Op = Opart + (size_t)slot * 4096;
    #pragma unroll
    for (int hs = 0; hs < 4; ++hs)
        *(f32x4*)(Op + (size_t)(wave * 16 + m16) * 64 + hs * 16 + quad * 4) = o[hs];
    if (quad == 0) {
        Ml[(size_t)slot * 128 + (wave * 16 + m16) * 2 + 0] = m_run;
        Ml[(size_t)slot * 128 + (wave * 16 + m16) * 2 + 1] = l_run;
    }
}

// Kernel 3: merge the <=8 slot-partials per q-tile (log-sum-exp weighting).
__global__ __launch_bounds__(256) void attn_merge(
    const float* __restrict__ Opart, const float* __restrict__ Ml,
    float* __restrict__ O)
{
    const int qt = blockIdx.x;
    const int b  = blockIdx.y;
    const int tid = threadIdx.x;
    const int row = tid >> 2;
    const int colblk = tid & 3;
    const int nc = (qt + 1 < 8) ? qt + 1 : 8;
    const int slotBase = (b * 32 + qt) * 8;

    f32x4 acc[4];
    #pragma unroll
    for (int j = 0; j < 4; ++j) acc[j] = {0.f, 0.f, 0.f, 0.f};
    float M = -1e30f, den = 0.f;

    for (int c = 0; c < nc; ++c) {
        const float* mlp = Ml + (size_t)(slotBase + c) * 128 + row * 2;
        const float mc = mlp[0];
        const float lc = mlp[1];
        const float newM  = fmaxf(M, mc);
        const float alpha = __expf(M - newM);
        const float w     = __expf(mc - newM);
        M = newM;

        const float* op = Opart + (size_t)(slotBase + c) * 4096 + row * 64 + colblk * 16;
        #pragma unroll
        for (int j = 0; j < 4; ++j) {
            f32x4 v = *(const f32x4*)(op + j * 4);
            #pragma unroll
            for (int e = 0; e < 4; ++e) acc[j][e] = acc[j][e] * alpha + w * v[e];
        }
        den = den * alpha + w * lc;
    }

    const float inv = 1.f / den;
    float* out = O + ((size_t)b * T_ + qt * 64 + row) * 64 + colblk * 16;
    #pragma unroll
    for (int j = 0; j < 4; ++j) {
        f32x4 v;
        #pragma unroll
        for (int e = 0; e < 4; ++e) v[e] = acc[j][e] * inv;
        *(f32x4*)(out + j * 4) = v;
    }
}

// ---------------------------------------------------------------------------
extern "C" void kernel_launch(void* const* d_in, const int* in_sizes, int n_in,
                              void* d_out, int out_size, void* d_ws, size_t ws_size,
                              hipStream_t stream)
{
    const float* x  = (const float*)d_in[0];
    const float* Wq = (const float*)d_in[1];
    const float* bq = (const float*)d_in[2];
    const float* Wk = (const float*)d_in[3];
    const float* bk = (const float*)d_in[4];
    const float* Wv = (const float*)d_in[5];
    const float* bv = (const float*)d_in[6];
    float* out = (float*)d_out;

    __bf16* Wp = (__bf16*)d_ws;              // 384*512 bf16         = 0.4 MB
    __bf16* Q  = Wp + 384 * 512;             // 8*2048*64 bf16       = 2 MB
    __bf16* K  = Q  + (size_t)B_ * T_ * HS_;
    __bf16* Vt = K  + (size_t)B_ * T_ * HS_; // transposed [b][h][t]
    float* Opart = (float*)(Vt + (size_t)B_ * T_ * HS_);  // 2048*4096 f32 = 33.6 MB
    float* Ml    = Opart + (size_t)2048 * 4096;           // 2048*128  f32 =  1 MB

    pack_w<<<96, 256, 0, stream>>>(Wq, Wk, Wv, Wp);
    qkv_fused<<<1024, 256, 0, stream>>>(x, Wp, bq, bk, bv, Q, K, Vt);
    attn_partial<<<dim3(8, 32, 8), 256, 0, stream>>>(Q, K, Vt, Opart, Ml);
    attn_merge<<<dim3(32, 8), 256, 0, stream>>>(Opart, Ml, out);
}